// Round 9
// baseline (1234.608 us; speedup 1.0000x reference)
//
#include <hip/hip_runtime.h>
#include <hip/hip_bf16.h>
#include <cstdint>

// Problem constants
// B=16, N=4096, S=1024 (NPOINT), K=32 (NSAMPLE), CIN=64, MLP 67->64->64->128
// M = B*S*K = 524288 rows through the MLP.

typedef __attribute__((ext_vector_type(8))) short bf16x8;
typedef __attribute__((ext_vector_type(4))) float f32x4;
typedef __attribute__((ext_vector_type(2))) float f32x2;

#define LDA 104   // bf16 LDS row stride: 208 B = 52 dwords -> 2-way (free) b128 bank pattern

__device__ __forceinline__ unsigned short f2bf(float f) {
  unsigned x = __float_as_uint(f);
  unsigned r = (x + 0x7FFFu + ((x >> 16) & 1u)) >> 16;  // RNE
  return (unsigned short)r;
}
__device__ __forceinline__ float bf2f(unsigned short u) {
  return __uint_as_float(((unsigned)u) << 16);
}

// DPP max-combine on a packed 64-bit key. DPP row ops are VALU-latency (~2-4cyc)
// vs ~120cyc for ds_permute-backed __shfl — this is the FPS critical path.
template <int CTRL>
__device__ __forceinline__ unsigned long long dppmax(unsigned long long k) {
  int lo = (int)(unsigned)k;
  int hi = (int)(unsigned)(k >> 32);
  int plo = __builtin_amdgcn_update_dpp(lo, lo, CTRL, 0xF, 0xF, false);
  int phi = __builtin_amdgcn_update_dpp(hi, hi, CTRL, 0xF, 0xF, false);
  unsigned long long o =
      ((unsigned long long)(unsigned)phi << 32) | (unsigned)plo;
  return (o > k) ? o : k;
}

// ---------------------------------------------------------------------------
// Fused FPS + prep, 256 threads/block. Blocks 0..15: FPS (one per batch).
// Blocks 16..1039: points transpose. Block 1040: weight tiles + stats zero.
//
// CONFIG HISTORY (measured): 256thr/4waves + waves_per_eu(1,1) = 614us (r7,
// best). 512thr/8waves = 666us (r8: waves are barrier-phase-locked, extra
// waves only add skew — latency hiding does NOT apply here). Default VGPR
// heuristic spills the 64-float point arrays (r3-r5); amdgpu_waves_per_eu(1,1)
// is the only knob that lifts the budget (r7: VGPR=132, no spill).
//
// ROUND 9: attack the two biggest chain terms at 1 wave/SIMD:
//  (a) dist issue (~400cyc): packed f32 (v_pk_sub/mul/add via float2 vectors,
//      #pragma clang fp contract(off) keeps each component a separate RN
//      mul/add — bit-identical to __f*_rn with the same association).
//  (b) argmax dependency tail (~128cyc): tree-structured (val,idx) combine,
//      strict > so a later index wins only if strictly greater — preserves
//      numpy first-occurrence semantics; depth 4 instead of 16.
//
// FPS per-iter serial chain: pk dist-update -> tree argmax -> DPP wave argmax
// (packed 64b key) -> lane63 writes key slot (double-buffered) -> ONE barrier
// -> all threads read 4 keys (2x b128) + 3-compare tree -> gi -> read center
// from LDS-staged xs/ys/zs. NO global stores in the loop (vmcnt(0) drain at
// the barrier); centers buffered in LDS, written at end. Index selection
// bit-identical to numpy (max dist, tie -> min n, key = bits(dist)<<32 | ~n).
// ---------------------------------------------------------------------------
__global__ __attribute__((amdgpu_flat_work_group_size(256, 256),
                          amdgpu_waves_per_eu(1, 1)))
void fps_prep_kernel(
    const float* __restrict__ xyz, const float* __restrict__ points,
    const float* __restrict__ W0, const float* __restrict__ W1,
    const float* __restrict__ W2, unsigned short* __restrict__ pT,
    unsigned short* __restrict__ w0t, unsigned short* __restrict__ w1t,
    unsigned short* __restrict__ w2t, float* __restrict__ stats_all,
    float* __restrict__ out, float4* __restrict__ centers4)
{
  __shared__ __align__(16) char smraw[61568];
  int tid = threadIdx.x;
  if (blockIdx.x >= 16) {
    int pb = blockIdx.x - 16;
    if (pb < 1024) {
      float (*tile)[65] = (float (*)[65])smraw;
      int b = pb >> 6;
      int n0 = (pb & 63) << 6;
      const float* pbp = points + ((size_t)b << 18);
      for (int i = tid; i < 4096; i += 256) {
        int cc = i >> 6, nn = i & 63;
        tile[cc][nn] = pbp[((size_t)cc << 12) + n0 + nn];
      }
      __syncthreads();
      for (int i = tid; i < 4096; i += 256) {
        int nn = i >> 6, cc = i & 63;
        pT[(((size_t)((b << 12) + n0 + nn)) << 6) + cc] = f2bf(tile[cc][nn]);
      }
    } else {
      // w0t: 64x104, w1t: 64x104, w2t: 128x104, stats: 512 floats
      for (int i = tid; i < 27136; i += 256) {
        if (i < 6656) {
          int nn = i / 104, kk = i % 104;
          float v = (kk < 64) ? W0[(3 + kk) * 64 + nn]
                              : ((kk < 67) ? W0[(kk - 64) * 64 + nn] : 0.f);
          w0t[i] = f2bf(v);
        } else if (i < 13312) {
          int j = i - 6656; int nn = j / 104, kk = j % 104;
          float v = (kk < 64) ? W1[kk * 64 + nn] : 0.f;
          w1t[j] = f2bf(v);
        } else if (i < 26624) {
          int j = i - 13312; int nn = j / 104, kk = j % 104;
          float v = (kk < 64) ? W2[kk * 128 + nn] : 0.f;
          w2t[j] = f2bf(v);
        } else {
          stats_all[i - 26624] = 0.f;
        }
      }
    }
    return;
  }
  // ---- FPS path ----
  float* xs  = (float*)smraw;                 // [4096]
  float* ys  = xs + 4096;                     // [4096]
  float* zs  = ys + 4096;                     // [4096]  (ends 49152 B)
  float* cxl = zs + 4096;                     // [1024]
  float* cyl = cxl + 1024;                    // [1024]
  float* czl = cyl + 1024;                    // [1024]  (ends 61440 B)
  unsigned long long (*keybuf)[4] =
      (unsigned long long (*)[4])(smraw + 61440);  // [2][4], 16B-aligned

  int b = blockIdx.x;
  const float* xb = xyz + (size_t)b * 12288;
  // pair p holds points n0 = tid + (2p)*256 (.x) and n0+256 (.y)
  f32x2 px2[8], py2[8], pz2[8], dist2[8];
#pragma unroll
  for (int p2 = 0; p2 < 8; ++p2) {
    int n0 = tid + (p2 << 9);
    float x0 = xb[n0], x1 = xb[n0 + 256];
    float y0 = xb[4096 + n0], y1 = xb[4096 + n0 + 256];
    float z0 = xb[8192 + n0], z1 = xb[8192 + n0 + 256];
    px2[p2] = (f32x2){x0, x1};
    py2[p2] = (f32x2){y0, y1};
    pz2[p2] = (f32x2){z0, z1};
    xs[n0] = x0; xs[n0 + 256] = x1;
    ys[n0] = y0; ys[n0 + 256] = y1;
    zs[n0] = z0; zs[n0 + 256] = z1;
    dist2[p2] = (f32x2){1e10f, 1e10f};
  }
  __syncthreads();
  float cx = xs[0], cy = ys[0], cz = zs[0];
  if (tid == 0) { cxl[0] = cx; cyl[0] = cy; czl[0] = cz; }
  int w = tid >> 6;
  int lane = tid & 63;
  for (int it = 1; it < 1024; ++it) {
    float bv; int bi;
    {
#pragma clang fp contract(off)
      // packed dist update: each component is a separate IEEE-RN mul/add in
      // the same ((dx*dx+dy*dy)+dz*dz) association as the reference.
      f32x2 c2x = (f32x2){cx, cx};
      f32x2 c2y = (f32x2){cy, cy};
      f32x2 c2z = (f32x2){cz, cz};
      f32x2 nd[8];
#pragma unroll
      for (int p2 = 0; p2 < 8; ++p2) {
        f32x2 dx = px2[p2] - c2x;
        f32x2 dy = py2[p2] - c2y;
        f32x2 dz = pz2[p2] - c2z;
        f32x2 xx = dx * dx;
        f32x2 yy = dy * dy;
        f32x2 zz = dz * dz;
        f32x2 d  = (xx + yy) + zz;
        f32x2 m;
        m.x = fminf(dist2[p2].x, d.x);
        m.y = fminf(dist2[p2].y, d.y);
        dist2[p2] = m;
        nd[p2] = m;
      }
      // tree argmax, first-occurrence: a later index wins only on strict >
      float v[8]; int ix[8];
#pragma unroll
      for (int p2 = 0; p2 < 8; ++p2) {
        int n0 = tid + (p2 << 9);
        bool t = nd[p2].y > nd[p2].x;
        v[p2]  = t ? nd[p2].y : nd[p2].x;
        ix[p2] = t ? (n0 + 256) : n0;
      }
#pragma unroll
      for (int st = 1; st < 8; st <<= 1) {
#pragma unroll
        for (int p2 = 0; p2 < 8; p2 += 2 * st) {
          bool t = v[p2 + st] > v[p2];
          v[p2]  = t ? v[p2 + st] : v[p2];
          ix[p2] = t ? ix[p2 + st] : ix[p2];
        }
      }
      bv = v[0]; bi = ix[0];
    }
    // pack: high 32 = dist bits (nonneg float => monotone), low 32 = ~n
    unsigned long long k =
        ((unsigned long long)__float_as_uint(bv) << 32) | (unsigned)(~bi);
    k = dppmax<0xB1>(k);    // quad_perm [1,0,3,2]  : xor 1
    k = dppmax<0x4E>(k);    // quad_perm [2,3,0,1]  : xor 2
    k = dppmax<0x141>(k);   // row_half_mirror      : xor 4
    k = dppmax<0x140>(k);   // row_mirror           : xor 8
    k = dppmax<0x142>(k);   // row_bcast15          : rows 0->1, 2->3
    k = dppmax<0x143>(k);   // row_bcast31          : rows 01 -> 23
    int p = it & 1;
    if (lane == 63) keybuf[p][w] = k;   // lane63 holds the wave max
    __syncthreads();
    // combine 4 wave keys: 2x b128 reads + 3-compare tree (uniform)
    uint4 ka2 = *(const uint4*)&keybuf[p][0];
    uint4 kb2 = *(const uint4*)&keybuf[p][2];
    unsigned long long k0 = ((unsigned long long)ka2.y << 32) | ka2.x;
    unsigned long long k1 = ((unsigned long long)ka2.w << 32) | ka2.z;
    unsigned long long k2 = ((unsigned long long)kb2.y << 32) | kb2.x;
    unsigned long long k3 = ((unsigned long long)kb2.w << 32) | kb2.z;
    unsigned long long m01 = (k1 > k0) ? k1 : k0;
    unsigned long long m23 = (k3 > k2) ? k3 : k2;
    unsigned long long km  = (m23 > m01) ? m23 : m01;
    int gi = (int)(~(unsigned)km) & 4095;
    cx = xs[gi]; cy = ys[gi]; cz = zs[gi];
    if (tid == 0) { cxl[it] = cx; cyl[it] = cy; czl[it] = cz; }
    // no second barrier: next iter writes keybuf[(it+1)&1], disjoint slot;
    // a wave re-writes this slot only after passing the NEXT barrier, which
    // orders it after every wave's read above.
  }
  __syncthreads();
  for (int it = tid; it < 1024; it += 256) {
    float x = cxl[it], y = cyl[it], z = czl[it];
    out[b * 3072 + it]        = x;
    out[b * 3072 + 1024 + it] = y;
    out[b * 3072 + 2048 + it] = z;
    centers4[(b << 10) + it]  = make_float4(x, y, z, 0.f);
  }
}

// ---------------------------------------------------------------------------
// Ball query, wave-per-center. Each wave scans 64 points/chunk for ONE
// center; __ballot(hit) + prefix popcount assigns ranks; ranks <32 store
// (ascending n => identical to the reference's sort-then-take-32). Early
// exit per wave when cnt>=32. Round 7: dropped ball from 630us out of top-5.
// ---------------------------------------------------------------------------
__global__ __launch_bounds__(256) void ball_kernel(const float* __restrict__ xyz,
                                                   const float4* __restrict__ centers4,
                                                   int* __restrict__ ballidx)
{
  __shared__ float xs[4096], ys[4096], zs[4096];
  int tid = threadIdx.x;
  int b = blockIdx.x >> 4;          // 16 blocks per batch
  int g = blockIdx.x & 15;          // 64-center group within batch
  const float* xb = xyz + (size_t)b * 12288;
  for (int i = tid; i < 4096; i += 256) {
    xs[i] = xb[i]; ys[i] = xb[4096 + i]; zs[i] = xb[8192 + i];
  }
  __syncthreads();
  int w = tid >> 6, lane = tid & 63;
  unsigned long long lmask = (1ull << lane) - 1ull;
  for (int j = 0; j < 16; ++j) {
    int s = (g << 6) + (j << 2) + w;          // wave-interleaved centers
    float4 c = centers4[(b << 10) + s];
    int* ob = ballidx + (((size_t)((b << 10) + s)) << 5);
    int cnt = 0, first = 0;
    for (int m = 0; m < 64; ++m) {
      int n = (m << 6) + lane;
      float dx = __fsub_rn(xs[n], c.x);
      float dy = __fsub_rn(ys[n], c.y);
      float dz = __fsub_rn(zs[n], c.z);
      float d  = __fadd_rn(__fadd_rn(__fmul_rn(dx, dx), __fmul_rn(dy, dy)),
                           __fmul_rn(dz, dz));
      bool hit = !(d > 0.04f);      // 0.04f == f32(RADIUS**2), matches ref
      unsigned long long mask = __ballot(hit);
      if (cnt == 0 && mask != 0ull)
        first = (m << 6) + (__ffsll((long long)mask) - 1);
      int p = cnt + (int)__popcll(mask & lmask);
      if (hit && p < 32) ob[p] = n;
      cnt += (int)__popcll(mask);
      if (cnt >= 32) break;
    }
    // tail fill (cnt uniform across the wave; center itself always hits so cnt>=1)
    if (lane < 32 && lane >= cnt) ob[lane] = first;
  }
}

// ---------------------------------------------------------------------------
// GEMM1: gather (pT rows + g_xyz) -> A[64 x 96(pad104)] bf16, W'T0, MFMA,
// write raw y1 bf16 [M,64] + per-block channel partials (sum, sumsq).
// ---------------------------------------------------------------------------
__global__ __launch_bounds__(256) void gemm1_kernel(
    const float* __restrict__ xyz, const unsigned short* __restrict__ pT,
    const unsigned short* __restrict__ w0t, const float* __restrict__ b0,
    const float4* __restrict__ centers4, const int* __restrict__ ballidx,
    unsigned short* __restrict__ feats1, float* __restrict__ partials)
{
  __shared__ unsigned short As[64 * LDA];
  __shared__ unsigned short Wt[64 * LDA];
  __shared__ float red[2][4][64];
  int tid = threadIdx.x;
  int rowbase = blockIdx.x << 6;
  int b = rowbase >> 15;
  {
    const uint4* wsrc = (const uint4*)w0t;
    uint4* wdst = (uint4*)Wt;
    for (int i = tid; i < 832; i += 256) wdst[i] = wsrc[i];
  }
  {
    int rl = tid >> 2, part = tid & 3;
    int r = rowbase + rl;
    int n = ballidx[r];
    const uint4* psrc = (const uint4*)(pT + (((size_t)((b << 12) + n)) << 6));
    uint4* adst = (uint4*)(As + rl * LDA);
    adst[part * 2]     = psrc[part * 2];
    adst[part * 2 + 1] = psrc[part * 2 + 1];
    adst[8 + part] = make_uint4(0, 0, 0, 0);   // zero cols 64..95
    if (part == 0) {
      int ci = r >> 5;
      float4 c = centers4[ci];
      unsigned short* arow = As + rl * LDA;
      arow[64] = f2bf(__fsub_rn(xyz[(size_t)b * 12288 + n],        c.x));
      arow[65] = f2bf(__fsub_rn(xyz[(size_t)b * 12288 + 4096 + n], c.y));
      arow[66] = f2bf(__fsub_rn(xyz[(size_t)b * 12288 + 8192 + n], c.z));
    }
  }
  __syncthreads();
  int lane = tid & 63, w = tid >> 6;
  int mrow = (w << 4) + (lane & 15);
  int quad = lane >> 4;
  f32x4 acc[4];
#pragma unroll
  for (int nt = 0; nt < 4; ++nt) acc[nt] = (f32x4){0.f, 0.f, 0.f, 0.f};
#pragma unroll
  for (int kt = 0; kt < 3; ++kt) {
    int ko = kt * 32 + (quad << 3);
    bf16x8 a = *(const bf16x8*)(As + mrow * LDA + ko);
#pragma unroll
    for (int nt = 0; nt < 4; ++nt) {
      bf16x8 bb = *(const bf16x8*)(Wt + ((nt << 4) + (lane & 15)) * LDA + ko);
      acc[nt] = __builtin_amdgcn_mfma_f32_16x16x32_bf16(a, bb, acc[nt], 0, 0, 0);
    }
  }
#pragma unroll
  for (int nt = 0; nt < 4; ++nt) {
    int cch = (nt << 4) + (lane & 15);
    float bias = b0[cch];
    float ssum = 0.f, sq = 0.f;
#pragma unroll
    for (int r2 = 0; r2 < 4; ++r2) {
      float y = acc[nt][r2] + bias;
      int ml = (w << 4) + (quad << 2) + r2;
      feats1[(((size_t)(rowbase + ml)) << 6) + cch] = f2bf(y);
      ssum += y; sq += y * y;
    }
    ssum += __shfl_xor(ssum, 16); ssum += __shfl_xor(ssum, 32);
    sq   += __shfl_xor(sq, 16);   sq   += __shfl_xor(sq, 32);
    if (quad == 0) { red[0][w][cch] = ssum; red[1][w][cch] = sq; }
  }
  __syncthreads();
  if (tid < 64) {
    float a0 = red[0][0][tid] + red[0][1][tid] + red[0][2][tid] + red[0][3][tid];
    float a1 = red[1][0][tid] + red[1][1][tid] + red[1][2][tid] + red[1][3][tid];
    partials[(size_t)blockIdx.x * 256 + tid]      = a0;
    partials[(size_t)blockIdx.x * 256 + 64 + tid] = a1;
  }
}

// ---------------------------------------------------------------------------
// GEMM2: A = relu(scale*y1+shift) from feats1; K=64; out raw y2 + partials.
// ---------------------------------------------------------------------------
__global__ __launch_bounds__(256) void gemm2_kernel(
    const unsigned short* __restrict__ featsIn, const unsigned short* __restrict__ wt,
    const float* __restrict__ bias_g, const float* __restrict__ ss_in,
    unsigned short* __restrict__ featsOut, float* __restrict__ partials)
{
  __shared__ unsigned short As[64 * LDA];
  __shared__ unsigned short Wt[64 * LDA];
  __shared__ float red[2][4][64];
  __shared__ float ssl[128];
  int tid = threadIdx.x;
  int rowbase = blockIdx.x << 6;
  if (tid < 128) ssl[tid] = ss_in[tid];
  {
    const uint4* wsrc = (const uint4*)wt;
    uint4* wdst = (uint4*)Wt;
    for (int i = tid; i < 832; i += 256) wdst[i] = wsrc[i];
  }
  __syncthreads();
  {
    int rl = tid >> 2, part = tid & 3;
    size_t r = (size_t)rowbase + rl;
    union { uint4 v[2]; unsigned short u[16]; } t;
    const uint4* src = (const uint4*)(featsIn + (r << 6));
    t.v[0] = src[part * 2]; t.v[1] = src[part * 2 + 1];
    union { uint4 v[2]; unsigned short u[16]; } o;
#pragma unroll
    for (int e = 0; e < 16; ++e) {
      int cch = (part << 4) + e;
      float f = bf2f(t.u[e]);
      float y = fmaxf(f * ssl[cch] + ssl[64 + cch], 0.f);
      o.u[e] = f2bf(y);
    }
    uint4* adst = (uint4*)(As + rl * LDA + (part << 4));
    adst[0] = o.v[0]; adst[1] = o.v[1];
  }
  __syncthreads();
  int lane = tid & 63, w = tid >> 6;
  int mrow = (w << 4) + (lane & 15);
  int quad = lane >> 4;
  f32x4 acc[4];
#pragma unroll
  for (int nt = 0; nt < 4; ++nt) acc[nt] = (f32x4){0.f, 0.f, 0.f, 0.f};
#pragma unroll
  for (int kt = 0; kt < 2; ++kt) {
    int ko = kt * 32 + (quad << 3);
    bf16x8 a = *(const bf16x8*)(As + mrow * LDA + ko);
#pragma unroll
    for (int nt = 0; nt < 4; ++nt) {
      bf16x8 bb = *(const bf16x8*)(Wt + ((nt << 4) + (lane & 15)) * LDA + ko);
      acc[nt] = __builtin_amdgcn_mfma_f32_16x16x32_bf16(a, bb, acc[nt], 0, 0, 0);
    }
  }
#pragma unroll
  for (int nt = 0; nt < 4; ++nt) {
    int cch = (nt << 4) + (lane & 15);
    float bias = bias_g[cch];
    float ssum = 0.f, sq = 0.f;
#pragma unroll
    for (int r2 = 0; r2 < 4; ++r2) {
      float y = acc[nt][r2] + bias;
      int ml = (w << 4) + (quad << 2) + r2;
      featsOut[(((size_t)(rowbase + ml)) << 6) + cch] = f2bf(y);
      ssum += y; sq += y * y;
    }
    ssum += __shfl_xor(ssum, 16); ssum += __shfl_xor(ssum, 32);
    sq   += __shfl_xor(sq, 16);   sq   += __shfl_xor(sq, 32);
    if (quad == 0) { red[0][w][cch] = ssum; red[1][w][cch] = sq; }
  }
  __syncthreads();
  if (tid < 64) {
    float a0 = red[0][0][tid] + red[0][1][tid] + red[0][2][tid] + red[0][3][tid];
    float a1 = red[1][0][tid] + red[1][1][tid] + red[1][2][tid] + red[1][3][tid];
    partials[(size_t)blockIdx.x * 256 + tid]      = a0;
    partials[(size_t)blockIdx.x * 256 + 64 + tid] = a1;
  }
}

// ---------------------------------------------------------------------------
// GEMM3 stats pass: y3 = relu2(feats2)@W2 + b2 ; only channel partials, no store.
// ---------------------------------------------------------------------------
__global__ __launch_bounds__(256) void gemm3_stats_kernel(
    const unsigned short* __restrict__ feats2, const unsigned short* __restrict__ w2t,
    const float* __restrict__ b2, const float* __restrict__ ss2,
    float* __restrict__ partials)
{
  __shared__ unsigned short As[64 * LDA];
  __shared__ unsigned short Wt[128 * LDA];
  __shared__ float red[2][4][128];
  __shared__ float ssl[128];
  int tid = threadIdx.x;
  int rowbase = blockIdx.x << 6;
  if (tid < 128) ssl[tid] = ss2[tid];
  {
    const uint4* wsrc = (const uint4*)w2t;
    uint4* wdst = (uint4*)Wt;
    for (int i = tid; i < 1664; i += 256) wdst[i] = wsrc[i];
  }
  __syncthreads();
  {
    int rl = tid >> 2, part = tid & 3;
    size_t r = (size_t)rowbase + rl;
    union { uint4 v[2]; unsigned short u[16]; } t;
    const uint4* src = (const uint4*)(feats2 + (r << 6));
    t.v[0] = src[part * 2]; t.v[1] = src[part * 2 + 1];
    union { uint4 v[2]; unsigned short u[16]; } o;
#pragma unroll
    for (int e = 0; e < 16; ++e) {
      int cch = (part << 4) + e;
      float f = bf2f(t.u[e]);
      float y = fmaxf(f * ssl[cch] + ssl[64 + cch], 0.f);
      o.u[e] = f2bf(y);
    }
    uint4* adst = (uint4*)(As + rl * LDA + (part << 4));
    adst[0] = o.v[0]; adst[1] = o.v[1];
  }
  __syncthreads();
  int lane = tid & 63, w = tid >> 6;
  int mrow = (w << 4) + (lane & 15);
  int quad = lane >> 4;
  f32x4 acc[8];
#pragma unroll
  for (int nt = 0; nt < 8; ++nt) acc[nt] = (f32x4){0.f, 0.f, 0.f, 0.f};
#pragma unroll
  for (int kt = 0; kt < 2; ++kt) {
    int ko = kt * 32 + (quad << 3);
    bf16x8 a = *(const bf16x8*)(As + mrow * LDA + ko);
#pragma unroll
    for (int nt = 0; nt < 8; ++nt) {
      bf16x8 bb = *(const bf16x8*)(Wt + ((nt << 4) + (lane & 15)) * LDA + ko);
      acc[nt] = __builtin_amdgcn_mfma_f32_16x16x32_bf16(a, bb, acc[nt], 0, 0, 0);
    }
  }
#pragma unroll
  for (int nt = 0; nt < 8; ++nt) {
    int cch = (nt << 4) + (lane & 15);
    float bias = b2[cch];
    float ssum = 0.f, sq = 0.f;
#pragma unroll
    for (int r2 = 0; r2 < 4; ++r2) {
      float y = acc[nt][r2] + bias;
      ssum += y; sq += y * y;
    }
    ssum += __shfl_xor(ssum, 16); ssum += __shfl_xor(ssum, 32);
    sq   += __shfl_xor(sq, 16);   sq   += __shfl_xor(sq, 32);
    if (quad == 0) { red[0][w][cch] = ssum; red[1][w][cch] = sq; }
  }
  __syncthreads();
  if (tid < 128) {
    float a0 = red[0][0][tid] + red[0][1][tid] + red[0][2][tid] + red[0][3][tid];
    float a1 = red[1][0][tid] + red[1][1][tid] + red[1][2][tid] + red[1][3][tid];
    partials[(size_t)blockIdx.x * 256 + tid]       = a0;
    partials[(size_t)blockIdx.x * 256 + 128 + tid] = a1;
  }
}

// ---------------------------------------------------------------------------
// Final: recompute y3, apply BN3+relu, max over K=32, write [B,S,128] compact.
// ---------------------------------------------------------------------------
__global__ __launch_bounds__(256) void final_kernel(
    const unsigned short* __restrict__ feats2, const unsigned short* __restrict__ w2t,
    const float* __restrict__ b2, const float* __restrict__ ss2,
    const float* __restrict__ ss3, float* __restrict__ out_tmp)
{
  __shared__ unsigned short As[64 * LDA];
  __shared__ unsigned short Wt[128 * LDA];
  __shared__ float ssl[128];
  __shared__ unsigned mx[2][128];
  int tid = threadIdx.x;
  int rowbase = blockIdx.x << 6;
  if (tid < 128) ssl[tid] = ss2[tid];
  ((unsigned*)mx)[tid] = 0u;   // relu outputs >= 0, so 0 == -inf here
  {
    const uint4* wsrc = (const uint4*)w2t;
    uint4* wdst = (uint4*)Wt;
    for (int i = tid; i < 1664; i += 256) wdst[i] = wsrc[i];
  }
  __syncthreads();
  {
    int rl = tid >> 2, part = tid & 3;
    size_t r = (size_t)rowbase + rl;
    union { uint4 v[2]; unsigned short u[16]; } t;
    const uint4* src = (const uint4*)(feats2 + (r << 6));
    t.v[0] = src[part * 2]; t.v[1] = src[part * 2 + 1];
    union { uint4 v[2]; unsigned short u[16]; } o;
#pragma unroll
    for (int e = 0; e < 16; ++e) {
      int cch = (part << 4) + e;
      float f = bf2f(t.u[e]);
      float y = fmaxf(f * ssl[cch] + ssl[64 + cch], 0.f);
      o.u[e] = f2bf(y);
    }
    uint4* adst = (uint4*)(As + rl * LDA + (part << 4));
    adst[0] = o.v[0]; adst[1] = o.v[1];
  }
  __syncthreads();
  int lane = tid & 63, w = tid >> 6;
  int mrow = (w << 4) + (lane & 15);
  int quad = lane >> 4;
  f32x4 acc[8];
#pragma unroll
  for (int nt = 0; nt < 8; ++nt) acc[nt] = (f32x4){0.f, 0.f, 0.f, 0.f};
#pragma unroll
  for (int kt = 0; kt < 2; ++kt) {
    int ko = kt * 32 + (quad << 3);
    bf16x8 a = *(const bf16x8*)(As + mrow * LDA + ko);
#pragma unroll
    for (int nt = 0; nt < 8; ++nt) {
      bf16x8 bb = *(const bf16x8*)(Wt + ((nt << 4) + (lane & 15)) * LDA + ko);
      acc[nt] = __builtin_amdgcn_mfma_f32_16x16x32_bf16(a, bb, acc[nt], 0, 0, 0);
    }
  }
  int cloc = w >> 1;   // rows 0..31 -> center 0, rows 32..63 -> center 1
#pragma unroll
  for (int nt = 0; nt < 8; ++nt) {
    int cch = (nt << 4) + (lane & 15);
    float bias = b2[cch];
    float sc = ss3[cch], sh = ss3[128 + cch];
    float m = 0.f;
#pragma unroll
    for (int r2 = 0; r2 < 4; ++r2) {
      float y = acc[nt][r2] + bias;
      float tv = fmaxf(y * sc + sh, 0.f);
      m = fmaxf(m, tv);
    }
    atomicMax(&mx[cloc][cch], __float_as_uint(m));
  }
  __syncthreads();
  {
    int c2 = tid >> 7, cch = tid & 127;
    float v = __uint_as_float(mx[c2][cch]);
    int cg = (rowbase >> 5) + c2;            // global center index b*1024+s
    out_tmp[((size_t)cg << 7) + cch] = v;
  }
}

// ---------------------------------------------------------------------------
// stats reduce + finalize
// ---------------------------------------------------------------------------
__global__ __launch_bounds__(256) void reduce_kernel(const float* __restrict__ partials,
                                                     float* __restrict__ stats, int twoC)
{
  int tid = threadIdx.x;
  if (tid < twoC) {
    int row0 = blockIdx.x << 7;
    float s = 0.f;
    for (int r = 0; r < 128; ++r) s += partials[((size_t)(row0 + r)) * 256 + tid];
    atomicAdd(&stats[tid], s);
  }
}

__global__ void finalize_kernel(const float* __restrict__ stats, const float* __restrict__ g,
                                const float* __restrict__ be, float* __restrict__ ss, int C)
{
  int c = threadIdx.x;
  if (c < C) {
    const float invM = 1.f / 524288.f;
    float mean = stats[c] * invM;
    float ex2  = stats[C + c] * invM;
    float var  = ex2 - mean * mean;
    float sc   = g[c] / sqrtf(var + 1e-5f);
    ss[c]     = sc;
    ss[C + c] = be[c] - mean * sc;
  }
}

// ---------------------------------------------------------------------------
// out_tmp [B,S,128] -> d_out [B,128,S] (offset 49152)
// ---------------------------------------------------------------------------
__global__ __launch_bounds__(256) void transpose_out_kernel(const float* __restrict__ out_tmp,
                                                            float* __restrict__ out)
{
  __shared__ float t2[64][65];
  int tid = threadIdx.x;
  int b = blockIdx.x >> 5;
  int rest = blockIdx.x & 31;
  int s0 = (rest & 15) << 6;
  int c0 = (rest >> 4) << 6;
  for (int i = tid; i < 4096; i += 256) {
    int row = i >> 6, col = i & 63;
    t2[row][col] = out_tmp[((size_t)((b << 10) + s0 + row)) * 128 + c0 + col];
  }
  __syncthreads();
  for (int i = tid; i < 4096; i += 256) {
    int crow = i >> 6, scol = i & 63;
    out[49152 + ((size_t)b << 17) + (size_t)(c0 + crow) * 1024 + s0 + scol] = t2[scol][crow];
  }
}

// ---------------------------------------------------------------------------
extern "C" void kernel_launch(void* const* d_in, const int* in_sizes, int n_in,
                              void* d_out, int out_size, void* d_ws, size_t ws_size,
                              hipStream_t stream)
{
  (void)in_sizes; (void)n_in; (void)out_size; (void)ws_size;
  const float* xyz    = (const float*)d_in[0];
  const float* points = (const float*)d_in[1];
  const float* W0  = (const float*)d_in[2];
  const float* b0  = (const float*)d_in[3];
  const float* g0  = (const float*)d_in[4];
  const float* be0 = (const float*)d_in[5];
  const float* W1  = (const float*)d_in[6];
  const float* b1  = (const float*)d_in[7];
  const float* g1  = (const float*)d_in[8];
  const float* be1 = (const float*)d_in[9];
  const float* W2  = (const float*)d_in[10];
  const float* b2  = (const float*)d_in[11];
  const float* g2  = (const float*)d_in[12];
  const float* be2 = (const float*)d_in[13];
  float* out = (float*)d_out;

  char* base = (char*)d_ws;
  size_t off = 0;
  auto alloc = [&](size_t bytes) -> void* {
    void* p = base + off;
    off += (bytes + 255) & ~(size_t)255;
    return p;
  };
  unsigned short* pT     = (unsigned short*)alloc((size_t)16 * 4096 * 64 * 2);
  unsigned short* w0t    = (unsigned short*)alloc(64 * LDA * 2);
  unsigned short* w1t    = (unsigned short*)alloc(64 * LDA * 2);
  unsigned short* w2t    = (unsigned short*)alloc(128 * LDA * 2);
  float* stats_all       = (float*)alloc(512 * 4);
  float* ss_all          = (float*)alloc(512 * 4);
  float4* centers4       = (float4*)alloc((size_t)16 * 1024 * 16);
  int* ballidx           = (int*)alloc((size_t)16 * 1024 * 32 * 4);
  unsigned short* feats1 = (unsigned short*)alloc((size_t)524288 * 64 * 2);
  unsigned short* feats2 = (unsigned short*)alloc((size_t)524288 * 64 * 2);
  float* partials        = (float*)alloc((size_t)8192 * 256 * 4);
  float* out_tmp         = (float*)alloc((size_t)16 * 1024 * 128 * 4);

  float* stats1 = stats_all;       float* stats2 = stats_all + 128; float* stats3 = stats_all + 256;
  float* ss1 = ss_all;             float* ss2 = ss_all + 128;       float* ss3 = ss_all + 256;

  fps_prep_kernel<<<1041, 256, 0, stream>>>(xyz, points, W0, W1, W2, pT, w0t, w1t,
                                            w2t, stats_all, out, centers4);
  ball_kernel<<<256, 256, 0, stream>>>(xyz, centers4, ballidx);
  gemm1_kernel<<<8192, 256, 0, stream>>>(xyz, pT, w0t, b0, centers4, ballidx, feats1, partials);
  reduce_kernel<<<64, 256, 0, stream>>>(partials, stats1, 128);
  finalize_kernel<<<1, 64, 0, stream>>>(stats1, g0, be0, ss1, 64);
  gemm2_kernel<<<8192, 256, 0, stream>>>(feats1, w1t, b1, ss1, feats2, partials);
  reduce_kernel<<<64, 256, 0, stream>>>(partials, stats2, 128);
  finalize_kernel<<<1, 64, 0, stream>>>(stats2, g1, be1, ss2, 64);
  gemm3_stats_kernel<<<8192, 256, 0, stream>>>(feats2, w2t, b2, ss2, partials);
  reduce_kernel<<<64, 256, 0, stream>>>(partials, stats3, 256);
  finalize_kernel<<<1, 128, 0, stream>>>(stats3, g2, be2, ss3, 128);
  final_kernel<<<8192, 256, 0, stream>>>(feats2, w2t, b2, ss2, ss3, out_tmp);
  transpose_out_kernel<<<512, 256, 0, stream>>>(out_tmp, out);
}

// Round 10
// 942.252 us; speedup vs baseline: 1.3103x; 1.3103x over previous
//
#include <hip/hip_runtime.h>
#include <hip/hip_bf16.h>
#include <cstdint>

// Problem constants
// B=16, N=4096, S=1024 (NPOINT), K=32 (NSAMPLE), CIN=64, MLP 67->64->64->128
// M = B*S*K = 524288 rows through the MLP.

typedef __attribute__((ext_vector_type(8))) short bf16x8;
typedef __attribute__((ext_vector_type(4))) float f32x4;

#define LDA 104   // bf16 LDS row stride: 208 B = 52 dwords -> 2-way (free) b128 bank pattern

__device__ __forceinline__ unsigned short f2bf(float f) {
  unsigned x = __float_as_uint(f);
  unsigned r = (x + 0x7FFFu + ((x >> 16) & 1u)) >> 16;  // RNE
  return (unsigned short)r;
}
__device__ __forceinline__ float bf2f(unsigned short u) {
  return __uint_as_float(((unsigned)u) << 16);
}

// DPP max-combine on a packed 64-bit key. DPP row ops are VALU-latency (~2-4cyc)
// vs ~120cyc for ds_permute-backed __shfl — this is the FPS critical path.
template <int CTRL>
__device__ __forceinline__ unsigned long long dppmax(unsigned long long k) {
  int lo = (int)(unsigned)k;
  int hi = (int)(unsigned)(k >> 32);
  int plo = __builtin_amdgcn_update_dpp(lo, lo, CTRL, 0xF, 0xF, false);
  int phi = __builtin_amdgcn_update_dpp(hi, hi, CTRL, 0xF, 0xF, false);
  unsigned long long o =
      ((unsigned long long)(unsigned)phi << 32) | (unsigned)plo;
  return (o > k) ? o : k;
}

// ---------------------------------------------------------------------------
// Fused FPS + prep, 256 threads/block. Blocks 0..15: FPS (one per batch).
// Blocks 16..1039: points transpose. Block 1040: weight tiles + stats zero.
//
// FPS STRUCTURAL FLOOR (r7-r9 measured): this exact kernel = 614us (r7).
// 8 waves = 666us (r8: barrier-phase-locked waves only add skew). Packed-f32
// + tree argmax = 879us (r9: f32x2 didn't map to clean v_pk, cndmask traffic
// doubled). The chain is 1024 serial iterations x ~1441cyc (dist issue ~416 +
// DPP + barrier + 2 dependent LDS rounds), confined to 1 CU/batch by the
// dist-state locality. Keep THIS version — do not re-tweak without disasm.
// amdgpu_waves_per_eu(1,1) is required: the default VGPR heuristic caps at
// 64 regs and spills the 64-float point arrays (r3-r5); launch_bounds cannot
// raise the max (r4).
// ---------------------------------------------------------------------------
__global__ __attribute__((amdgpu_flat_work_group_size(256, 256),
                          amdgpu_waves_per_eu(1, 1)))
void fps_prep_kernel(
    const float* __restrict__ xyz, const float* __restrict__ points,
    const float* __restrict__ W0, const float* __restrict__ W1,
    const float* __restrict__ W2, unsigned short* __restrict__ pT,
    unsigned short* __restrict__ w0t, unsigned short* __restrict__ w1t,
    unsigned short* __restrict__ w2t, float* __restrict__ stats_all,
    float* __restrict__ out, float4* __restrict__ centers4)
{
  __shared__ __align__(16) char smraw[61568];
  int tid = threadIdx.x;
  if (blockIdx.x >= 16) {
    int pb = blockIdx.x - 16;
    if (pb < 1024) {
      float (*tile)[65] = (float (*)[65])smraw;
      int b = pb >> 6;
      int n0 = (pb & 63) << 6;
      const float* pbp = points + ((size_t)b << 18);
      for (int i = tid; i < 4096; i += 256) {
        int cc = i >> 6, nn = i & 63;
        tile[cc][nn] = pbp[((size_t)cc << 12) + n0 + nn];
      }
      __syncthreads();
      for (int i = tid; i < 4096; i += 256) {
        int nn = i >> 6, cc = i & 63;
        pT[(((size_t)((b << 12) + n0 + nn)) << 6) + cc] = f2bf(tile[cc][nn]);
      }
    } else {
      // w0t: 64x104, w1t: 64x104, w2t: 128x104, stats: 512 floats
      for (int i = tid; i < 27136; i += 256) {
        if (i < 6656) {
          int nn = i / 104, kk = i % 104;
          float v = (kk < 64) ? W0[(3 + kk) * 64 + nn]
                              : ((kk < 67) ? W0[(kk - 64) * 64 + nn] : 0.f);
          w0t[i] = f2bf(v);
        } else if (i < 13312) {
          int j = i - 6656; int nn = j / 104, kk = j % 104;
          float v = (kk < 64) ? W1[kk * 64 + nn] : 0.f;
          w1t[j] = f2bf(v);
        } else if (i < 26624) {
          int j = i - 13312; int nn = j / 104, kk = j % 104;
          float v = (kk < 64) ? W2[kk * 128 + nn] : 0.f;
          w2t[j] = f2bf(v);
        } else {
          stats_all[i - 26624] = 0.f;
        }
      }
    }
    return;
  }
  // ---- FPS path ----
  float* xs  = (float*)smraw;                 // [4096]
  float* ys  = xs + 4096;                     // [4096]
  float* zs  = ys + 4096;                     // [4096]  (ends 49152 B)
  float* cxl = zs + 4096;                     // [1024]
  float* cyl = cxl + 1024;                    // [1024]
  float* czl = cyl + 1024;                    // [1024]  (ends 61440 B)
  unsigned long long (*keybuf)[4] =
      (unsigned long long (*)[4])(smraw + 61440);  // [2][4], 16B-aligned

  int b = blockIdx.x;
  const float* xb = xyz + (size_t)b * 12288;
  float px[16], py[16], pz[16], dist[16];
#pragma unroll
  for (int j = 0; j < 16; ++j) {
    int n = tid + (j << 8);
    px[j] = xb[n]; py[j] = xb[4096 + n]; pz[j] = xb[8192 + n];
    xs[n] = px[j]; ys[n] = py[j]; zs[n] = pz[j];
    dist[j] = 1e10f;
  }
  __syncthreads();
  float cx = xs[0], cy = ys[0], cz = zs[0];
  if (tid == 0) { cxl[0] = cx; cyl[0] = cy; czl[0] = cz; }
  int w = tid >> 6;
  int lane = tid & 63;
  for (int it = 1; it < 1024; ++it) {
    float bv = -1.f; int bi = 0;
#pragma unroll
    for (int j = 0; j < 16; ++j) {
      float dx = __fsub_rn(px[j], cx);
      float dy = __fsub_rn(py[j], cy);
      float dz = __fsub_rn(pz[j], cz);
      float d  = __fadd_rn(__fadd_rn(__fmul_rn(dx, dx), __fmul_rn(dy, dy)),
                           __fmul_rn(dz, dz));
      float nd = fminf(dist[j], d);
      dist[j] = nd;
      if (nd > bv) { bv = nd; bi = tid + (j << 8); }  // strict >, j asc => min n
    }
    // pack: high 32 = dist bits (nonneg float => monotone), low 32 = ~n
    unsigned long long k =
        ((unsigned long long)__float_as_uint(bv) << 32) | (unsigned)(~bi);
    k = dppmax<0xB1>(k);    // quad_perm [1,0,3,2]  : xor 1
    k = dppmax<0x4E>(k);    // quad_perm [2,3,0,1]  : xor 2
    k = dppmax<0x141>(k);   // row_half_mirror      : xor 4
    k = dppmax<0x140>(k);   // row_mirror           : xor 8
    k = dppmax<0x142>(k);   // row_bcast15          : rows 0->1, 2->3
    k = dppmax<0x143>(k);   // row_bcast31          : rows 01 -> 23
    int p = it & 1;
    if (lane == 63) keybuf[p][w] = k;   // lane63 holds the wave max
    __syncthreads();
    // combine 4 wave keys: 2x b128 reads + 3-compare tree (uniform)
    uint4 ka2 = *(const uint4*)&keybuf[p][0];
    uint4 kb2 = *(const uint4*)&keybuf[p][2];
    unsigned long long k0 = ((unsigned long long)ka2.y << 32) | ka2.x;
    unsigned long long k1 = ((unsigned long long)ka2.w << 32) | ka2.z;
    unsigned long long k2 = ((unsigned long long)kb2.y << 32) | kb2.x;
    unsigned long long k3 = ((unsigned long long)kb2.w << 32) | kb2.z;
    unsigned long long m01 = (k1 > k0) ? k1 : k0;
    unsigned long long m23 = (k3 > k2) ? k3 : k2;
    unsigned long long km  = (m23 > m01) ? m23 : m01;
    int gi = (int)(~(unsigned)km) & 4095;
    cx = xs[gi]; cy = ys[gi]; cz = zs[gi];
    if (tid == 0) { cxl[it] = cx; cyl[it] = cy; czl[it] = cz; }
    // no second barrier: next iter writes keybuf[(it+1)&1], disjoint slot;
    // a wave re-writes this slot only after passing the NEXT barrier, which
    // orders it after every wave's read above.
  }
  __syncthreads();
  for (int it = tid; it < 1024; it += 256) {
    float x = cxl[it], y = cyl[it], z = czl[it];
    out[b * 3072 + it]        = x;
    out[b * 3072 + 1024 + it] = y;
    out[b * 3072 + 2048 + it] = z;
    centers4[(b << 10) + it]  = make_float4(x, y, z, 0.f);
  }
}

// ---------------------------------------------------------------------------
// Ball query, wave-per-center. Each wave scans 64 points/chunk for ONE
// center; __ballot(hit) + prefix popcount assigns ranks; ranks <32 store
// (ascending n => identical to the reference's sort-then-take-32). Early
// exit per wave when cnt>=32. Round 7: dropped ball from 630us out of top-5.
// ---------------------------------------------------------------------------
__global__ __launch_bounds__(256) void ball_kernel(const float* __restrict__ xyz,
                                                   const float4* __restrict__ centers4,
                                                   int* __restrict__ ballidx)
{
  __shared__ float xs[4096], ys[4096], zs[4096];
  int tid = threadIdx.x;
  int b = blockIdx.x >> 4;          // 16 blocks per batch
  int g = blockIdx.x & 15;          // 64-center group within batch
  const float* xb = xyz + (size_t)b * 12288;
  for (int i = tid; i < 4096; i += 256) {
    xs[i] = xb[i]; ys[i] = xb[4096 + i]; zs[i] = xb[8192 + i];
  }
  __syncthreads();
  int w = tid >> 6, lane = tid & 63;
  unsigned long long lmask = (1ull << lane) - 1ull;
  for (int j = 0; j < 16; ++j) {
    int s = (g << 6) + (j << 2) + w;          // wave-interleaved centers
    float4 c = centers4[(b << 10) + s];
    int* ob = ballidx + (((size_t)((b << 10) + s)) << 5);
    int cnt = 0, first = 0;
    for (int m = 0; m < 64; ++m) {
      int n = (m << 6) + lane;
      float dx = __fsub_rn(xs[n], c.x);
      float dy = __fsub_rn(ys[n], c.y);
      float dz = __fsub_rn(zs[n], c.z);
      float d  = __fadd_rn(__fadd_rn(__fmul_rn(dx, dx), __fmul_rn(dy, dy)),
                           __fmul_rn(dz, dz));
      bool hit = !(d > 0.04f);      // 0.04f == f32(RADIUS**2), matches ref
      unsigned long long mask = __ballot(hit);
      if (cnt == 0 && mask != 0ull)
        first = (m << 6) + (__ffsll((long long)mask) - 1);
      int p = cnt + (int)__popcll(mask & lmask);
      if (hit && p < 32) ob[p] = n;
      cnt += (int)__popcll(mask);
      if (cnt >= 32) break;
    }
    // tail fill (cnt uniform across the wave; center itself always hits so cnt>=1)
    if (lane < 32 && lane >= cnt) ob[lane] = first;
  }
}

// ---------------------------------------------------------------------------
// GEMM1: gather (pT rows + g_xyz) -> A[64 x 96(pad104)] bf16, W'T0, MFMA,
// write raw y1 bf16 [M,64] + per-block channel partials (sum, sumsq).
// ---------------------------------------------------------------------------
__global__ __launch_bounds__(256) void gemm1_kernel(
    const float* __restrict__ xyz, const unsigned short* __restrict__ pT,
    const unsigned short* __restrict__ w0t, const float* __restrict__ b0,
    const float4* __restrict__ centers4, const int* __restrict__ ballidx,
    unsigned short* __restrict__ feats1, float* __restrict__ partials)
{
  __shared__ unsigned short As[64 * LDA];
  __shared__ unsigned short Wt[64 * LDA];
  __shared__ float red[2][4][64];
  int tid = threadIdx.x;
  int rowbase = blockIdx.x << 6;
  int b = rowbase >> 15;
  {
    const uint4* wsrc = (const uint4*)w0t;
    uint4* wdst = (uint4*)Wt;
    for (int i = tid; i < 832; i += 256) wdst[i] = wsrc[i];
  }
  {
    int rl = tid >> 2, part = tid & 3;
    int r = rowbase + rl;
    int n = ballidx[r];
    const uint4* psrc = (const uint4*)(pT + (((size_t)((b << 12) + n)) << 6));
    uint4* adst = (uint4*)(As + rl * LDA);
    adst[part * 2]     = psrc[part * 2];
    adst[part * 2 + 1] = psrc[part * 2 + 1];
    adst[8 + part] = make_uint4(0, 0, 0, 0);   // zero cols 64..95
    if (part == 0) {
      int ci = r >> 5;
      float4 c = centers4[ci];
      unsigned short* arow = As + rl * LDA;
      arow[64] = f2bf(__fsub_rn(xyz[(size_t)b * 12288 + n],        c.x));
      arow[65] = f2bf(__fsub_rn(xyz[(size_t)b * 12288 + 4096 + n], c.y));
      arow[66] = f2bf(__fsub_rn(xyz[(size_t)b * 12288 + 8192 + n], c.z));
    }
  }
  __syncthreads();
  int lane = tid & 63, w = tid >> 6;
  int mrow = (w << 4) + (lane & 15);
  int quad = lane >> 4;
  f32x4 acc[4];
#pragma unroll
  for (int nt = 0; nt < 4; ++nt) acc[nt] = (f32x4){0.f, 0.f, 0.f, 0.f};
#pragma unroll
  for (int kt = 0; kt < 3; ++kt) {
    int ko = kt * 32 + (quad << 3);
    bf16x8 a = *(const bf16x8*)(As + mrow * LDA + ko);
#pragma unroll
    for (int nt = 0; nt < 4; ++nt) {
      bf16x8 bb = *(const bf16x8*)(Wt + ((nt << 4) + (lane & 15)) * LDA + ko);
      acc[nt] = __builtin_amdgcn_mfma_f32_16x16x32_bf16(a, bb, acc[nt], 0, 0, 0);
    }
  }
#pragma unroll
  for (int nt = 0; nt < 4; ++nt) {
    int cch = (nt << 4) + (lane & 15);
    float bias = b0[cch];
    float ssum = 0.f, sq = 0.f;
#pragma unroll
    for (int r2 = 0; r2 < 4; ++r2) {
      float y = acc[nt][r2] + bias;
      int ml = (w << 4) + (quad << 2) + r2;
      feats1[(((size_t)(rowbase + ml)) << 6) + cch] = f2bf(y);
      ssum += y; sq += y * y;
    }
    ssum += __shfl_xor(ssum, 16); ssum += __shfl_xor(ssum, 32);
    sq   += __shfl_xor(sq, 16);   sq   += __shfl_xor(sq, 32);
    if (quad == 0) { red[0][w][cch] = ssum; red[1][w][cch] = sq; }
  }
  __syncthreads();
  if (tid < 64) {
    float a0 = red[0][0][tid] + red[0][1][tid] + red[0][2][tid] + red[0][3][tid];
    float a1 = red[1][0][tid] + red[1][1][tid] + red[1][2][tid] + red[1][3][tid];
    partials[(size_t)blockIdx.x * 256 + tid]      = a0;
    partials[(size_t)blockIdx.x * 256 + 64 + tid] = a1;
  }
}

// ---------------------------------------------------------------------------
// GEMM2: A = relu(scale*y1+shift) from feats1; K=64; out raw y2 + partials.
// ---------------------------------------------------------------------------
__global__ __launch_bounds__(256) void gemm2_kernel(
    const unsigned short* __restrict__ featsIn, const unsigned short* __restrict__ wt,
    const float* __restrict__ bias_g, const float* __restrict__ ss_in,
    unsigned short* __restrict__ featsOut, float* __restrict__ partials)
{
  __shared__ unsigned short As[64 * LDA];
  __shared__ unsigned short Wt[64 * LDA];
  __shared__ float red[2][4][64];
  __shared__ float ssl[128];
  int tid = threadIdx.x;
  int rowbase = blockIdx.x << 6;
  if (tid < 128) ssl[tid] = ss_in[tid];
  {
    const uint4* wsrc = (const uint4*)wt;
    uint4* wdst = (uint4*)Wt;
    for (int i = tid; i < 832; i += 256) wdst[i] = wsrc[i];
  }
  __syncthreads();
  {
    int rl = tid >> 2, part = tid & 3;
    size_t r = (size_t)rowbase + rl;
    union { uint4 v[2]; unsigned short u[16]; } t;
    const uint4* src = (const uint4*)(featsIn + (r << 6));
    t.v[0] = src[part * 2]; t.v[1] = src[part * 2 + 1];
    union { uint4 v[2]; unsigned short u[16]; } o;
#pragma unroll
    for (int e = 0; e < 16; ++e) {
      int cch = (part << 4) + e;
      float f = bf2f(t.u[e]);
      float y = fmaxf(f * ssl[cch] + ssl[64 + cch], 0.f);
      o.u[e] = f2bf(y);
    }
    uint4* adst = (uint4*)(As + rl * LDA + (part << 4));
    adst[0] = o.v[0]; adst[1] = o.v[1];
  }
  __syncthreads();
  int lane = tid & 63, w = tid >> 6;
  int mrow = (w << 4) + (lane & 15);
  int quad = lane >> 4;
  f32x4 acc[4];
#pragma unroll
  for (int nt = 0; nt < 4; ++nt) acc[nt] = (f32x4){0.f, 0.f, 0.f, 0.f};
#pragma unroll
  for (int kt = 0; kt < 2; ++kt) {
    int ko = kt * 32 + (quad << 3);
    bf16x8 a = *(const bf16x8*)(As + mrow * LDA + ko);
#pragma unroll
    for (int nt = 0; nt < 4; ++nt) {
      bf16x8 bb = *(const bf16x8*)(Wt + ((nt << 4) + (lane & 15)) * LDA + ko);
      acc[nt] = __builtin_amdgcn_mfma_f32_16x16x32_bf16(a, bb, acc[nt], 0, 0, 0);
    }
  }
#pragma unroll
  for (int nt = 0; nt < 4; ++nt) {
    int cch = (nt << 4) + (lane & 15);
    float bias = bias_g[cch];
    float ssum = 0.f, sq = 0.f;
#pragma unroll
    for (int r2 = 0; r2 < 4; ++r2) {
      float y = acc[nt][r2] + bias;
      int ml = (w << 4) + (quad << 2) + r2;
      featsOut[(((size_t)(rowbase + ml)) << 6) + cch] = f2bf(y);
      ssum += y; sq += y * y;
    }
    ssum += __shfl_xor(ssum, 16); ssum += __shfl_xor(ssum, 32);
    sq   += __shfl_xor(sq, 16);   sq   += __shfl_xor(sq, 32);
    if (quad == 0) { red[0][w][cch] = ssum; red[1][w][cch] = sq; }
  }
  __syncthreads();
  if (tid < 64) {
    float a0 = red[0][0][tid] + red[0][1][tid] + red[0][2][tid] + red[0][3][tid];
    float a1 = red[1][0][tid] + red[1][1][tid] + red[1][2][tid] + red[1][3][tid];
    partials[(size_t)blockIdx.x * 256 + tid]      = a0;
    partials[(size_t)blockIdx.x * 256 + 64 + tid] = a1;
  }
}

// ---------------------------------------------------------------------------
// GEMM3 stats + K-extremes pass (round 10): y3 = relu2(feats2)@W2 + b2.
// Writes channel partials (sum, sumsq) AND per-(center,channel) max & min of
// raw y3. This makes final_kernel (a second full 67MB feats2 read + GEMM)
// redundant: max_k relu(sc*y+sh) == relu(sc*(sc>=0?max_k y:min_k y)+sh)
// bit-exactly, because IEEE-RN mul/add are weakly monotone and the winning
// element's expression is evaluated identically in the epilogue.
// ---------------------------------------------------------------------------
__global__ __launch_bounds__(256) void gemm3_stats_kernel(
    const unsigned short* __restrict__ feats2, const unsigned short* __restrict__ w2t,
    const float* __restrict__ b2, const float* __restrict__ ss2,
    float* __restrict__ partials, float* __restrict__ y3mx,
    float* __restrict__ y3mn)
{
  __shared__ unsigned short As[64 * LDA];
  __shared__ unsigned short Wt[128 * LDA];
  __shared__ float red[2][4][128];
  __shared__ float mxw[4][128];
  __shared__ float mnw[4][128];
  __shared__ float ssl[128];
  int tid = threadIdx.x;
  int rowbase = blockIdx.x << 6;
  if (tid < 128) ssl[tid] = ss2[tid];
  {
    const uint4* wsrc = (const uint4*)w2t;
    uint4* wdst = (uint4*)Wt;
    for (int i = tid; i < 1664; i += 256) wdst[i] = wsrc[i];
  }
  __syncthreads();
  {
    int rl = tid >> 2, part = tid & 3;
    size_t r = (size_t)rowbase + rl;
    union { uint4 v[2]; unsigned short u[16]; } t;
    const uint4* src = (const uint4*)(feats2 + (r << 6));
    t.v[0] = src[part * 2]; t.v[1] = src[part * 2 + 1];
    union { uint4 v[2]; unsigned short u[16]; } o;
#pragma unroll
    for (int e = 0; e < 16; ++e) {
      int cch = (part << 4) + e;
      float f = bf2f(t.u[e]);
      float y = fmaxf(f * ssl[cch] + ssl[64 + cch], 0.f);
      o.u[e] = f2bf(y);
    }
    uint4* adst = (uint4*)(As + rl * LDA + (part << 4));
    adst[0] = o.v[0]; adst[1] = o.v[1];
  }
  __syncthreads();
  int lane = tid & 63, w = tid >> 6;
  int mrow = (w << 4) + (lane & 15);
  int quad = lane >> 4;
  f32x4 acc[8];
#pragma unroll
  for (int nt = 0; nt < 8; ++nt) acc[nt] = (f32x4){0.f, 0.f, 0.f, 0.f};
#pragma unroll
  for (int kt = 0; kt < 2; ++kt) {
    int ko = kt * 32 + (quad << 3);
    bf16x8 a = *(const bf16x8*)(As + mrow * LDA + ko);
#pragma unroll
    for (int nt = 0; nt < 8; ++nt) {
      bf16x8 bb = *(const bf16x8*)(Wt + ((nt << 4) + (lane & 15)) * LDA + ko);
      acc[nt] = __builtin_amdgcn_mfma_f32_16x16x32_bf16(a, bb, acc[nt], 0, 0, 0);
    }
  }
  // all 16 rows touched by wave w belong to one center (w*16..w*16+15 within
  // the 64-row block; center = w>>1) — so cross-quad shfl + per-wave LDS slot
  // suffices for the K-extremes.
#pragma unroll
  for (int nt = 0; nt < 8; ++nt) {
    int cch = (nt << 4) + (lane & 15);
    float bias = b2[cch];
    float ssum = 0.f, sq = 0.f;
    float mx = -3.4e38f, mn = 3.4e38f;
#pragma unroll
    for (int r2 = 0; r2 < 4; ++r2) {
      float y = acc[nt][r2] + bias;
      ssum += y; sq += y * y;
      mx = fmaxf(mx, y); mn = fminf(mn, y);
    }
    ssum += __shfl_xor(ssum, 16); ssum += __shfl_xor(ssum, 32);
    sq   += __shfl_xor(sq, 16);   sq   += __shfl_xor(sq, 32);
    mx = fmaxf(mx, __shfl_xor(mx, 16)); mx = fmaxf(mx, __shfl_xor(mx, 32));
    mn = fminf(mn, __shfl_xor(mn, 16)); mn = fminf(mn, __shfl_xor(mn, 32));
    if (quad == 0) {
      red[0][w][cch] = ssum; red[1][w][cch] = sq;
      mxw[w][cch] = mx; mnw[w][cch] = mn;
    }
  }
  __syncthreads();
  if (tid < 128) {
    float a0 = red[0][0][tid] + red[0][1][tid] + red[0][2][tid] + red[0][3][tid];
    float a1 = red[1][0][tid] + red[1][1][tid] + red[1][2][tid] + red[1][3][tid];
    partials[(size_t)blockIdx.x * 256 + tid]       = a0;
    partials[(size_t)blockIdx.x * 256 + 128 + tid] = a1;
  }
  {
    int c2 = tid >> 7, cch = tid & 127;
    int cg = (rowbase >> 5) + c2;            // global center index b*1024+s
    y3mx[((size_t)cg << 7) + cch] = fmaxf(mxw[2 * c2][cch], mxw[2 * c2 + 1][cch]);
    y3mn[((size_t)cg << 7) + cch] = fminf(mnw[2 * c2][cch], mnw[2 * c2 + 1][cch]);
  }
}

// ---------------------------------------------------------------------------
// stats reduce + finalize
// ---------------------------------------------------------------------------
__global__ __launch_bounds__(256) void reduce_kernel(const float* __restrict__ partials,
                                                     float* __restrict__ stats, int twoC)
{
  int tid = threadIdx.x;
  if (tid < twoC) {
    int row0 = blockIdx.x << 7;
    float s = 0.f;
    for (int r = 0; r < 128; ++r) s += partials[((size_t)(row0 + r)) * 256 + tid];
    atomicAdd(&stats[tid], s);
  }
}

__global__ void finalize_kernel(const float* __restrict__ stats, const float* __restrict__ g,
                                const float* __restrict__ be, float* __restrict__ ss, int C)
{
  int c = threadIdx.x;
  if (c < C) {
    const float invM = 1.f / 524288.f;
    float mean = stats[c] * invM;
    float ex2  = stats[C + c] * invM;
    float var  = ex2 - mean * mean;
    float sc   = g[c] / sqrtf(var + 1e-5f);
    ss[c]     = sc;
    ss[C + c] = be[c] - mean * sc;
  }
}

// ---------------------------------------------------------------------------
// BN3 + K-max epilogue + transpose (round 10, replaces final_kernel AND
// transpose_out_kernel): read y3mx/y3mn [B*S,128], pick extreme by sign(sc),
// apply relu(sc*y+sh), write d_out [B,128,S] (offset 49152) transposed.
// ---------------------------------------------------------------------------
__global__ __launch_bounds__(256) void bn3_out_kernel(
    const float* __restrict__ y3mx, const float* __restrict__ y3mn,
    const float* __restrict__ ss3, float* __restrict__ out)
{
  __shared__ float t2[64][65];
  __shared__ float sl[128];
  int tid = threadIdx.x;
  int b = blockIdx.x >> 5;
  int rest = blockIdx.x & 31;
  int s0 = (rest & 15) << 6;
  int c0 = (rest >> 4) << 6;
  if (tid < 64) sl[tid] = ss3[c0 + tid];
  else if (tid < 128) sl[tid] = ss3[128 + c0 + (tid - 64)];
  __syncthreads();
  for (int i = tid; i < 4096; i += 256) {
    int row = i >> 6, col = i & 63;         // row = s within tile, col = ch
    size_t cg = (size_t)((b << 10) + s0 + row);
    float mx = y3mx[(cg << 7) + c0 + col];
    float mn = y3mn[(cg << 7) + c0 + col];
    float sc = sl[col], sh = sl[64 + col];
    float ye = (sc >= 0.f) ? mx : mn;
    t2[row][col] = fmaxf(ye * sc + sh, 0.f);
  }
  __syncthreads();
  for (int i = tid; i < 4096; i += 256) {
    int crow = i >> 6, scol = i & 63;
    out[49152 + ((size_t)b << 17) + (size_t)(c0 + crow) * 1024 + s0 + scol] = t2[scol][crow];
  }
}

// ---------------------------------------------------------------------------
extern "C" void kernel_launch(void* const* d_in, const int* in_sizes, int n_in,
                              void* d_out, int out_size, void* d_ws, size_t ws_size,
                              hipStream_t stream)
{
  (void)in_sizes; (void)n_in; (void)out_size; (void)ws_size;
  const float* xyz    = (const float*)d_in[0];
  const float* points = (const float*)d_in[1];
  const float* W0  = (const float*)d_in[2];
  const float* b0  = (const float*)d_in[3];
  const float* g0  = (const float*)d_in[4];
  const float* be0 = (const float*)d_in[5];
  const float* W1  = (const float*)d_in[6];
  const float* b1  = (const float*)d_in[7];
  const float* g1  = (const float*)d_in[8];
  const float* be1 = (const float*)d_in[9];
  const float* W2  = (const float*)d_in[10];
  const float* b2  = (const float*)d_in[11];
  const float* g2  = (const float*)d_in[12];
  const float* be2 = (const float*)d_in[13];
  float* out = (float*)d_out;

  char* base = (char*)d_ws;
  size_t off = 0;
  auto alloc = [&](size_t bytes) -> void* {
    void* p = base + off;
    off += (bytes + 255) & ~(size_t)255;
    return p;
  };
  unsigned short* pT     = (unsigned short*)alloc((size_t)16 * 4096 * 64 * 2);
  unsigned short* w0t    = (unsigned short*)alloc(64 * LDA * 2);
  unsigned short* w1t    = (unsigned short*)alloc(64 * LDA * 2);
  unsigned short* w2t    = (unsigned short*)alloc(128 * LDA * 2);
  float* stats_all       = (float*)alloc(512 * 4);
  float* ss_all          = (float*)alloc(512 * 4);
  float4* centers4       = (float4*)alloc((size_t)16 * 1024 * 16);
  int* ballidx           = (int*)alloc((size_t)16 * 1024 * 32 * 4);
  unsigned short* feats1 = (unsigned short*)alloc((size_t)524288 * 64 * 2);
  unsigned short* feats2 = (unsigned short*)alloc((size_t)524288 * 64 * 2);
  float* partials        = (float*)alloc((size_t)8192 * 256 * 4);

  // y3 extremes overlay the dead feats1 buffer (feats1 is fully consumed by
  // gemm2 before gemm3_stats runs; 2 x 8.4MB fits in feats1's 67MB).
  float* y3mx = (float*)feats1;
  float* y3mn = y3mx + (size_t)16384 * 128;

  float* stats1 = stats_all;       float* stats2 = stats_all + 128; float* stats3 = stats_all + 256;
  float* ss1 = ss_all;             float* ss2 = ss_all + 128;       float* ss3 = ss_all + 256;

  fps_prep_kernel<<<1041, 256, 0, stream>>>(xyz, points, W0, W1, W2, pT, w0t, w1t,
                                            w2t, stats_all, out, centers4);
  ball_kernel<<<256, 256, 0, stream>>>(xyz, centers4, ballidx);
  gemm1_kernel<<<8192, 256, 0, stream>>>(xyz, pT, w0t, b0, centers4, ballidx, feats1, partials);
  reduce_kernel<<<64, 256, 0, stream>>>(partials, stats1, 128);
  finalize_kernel<<<1, 64, 0, stream>>>(stats1, g0, be0, ss1, 64);
  gemm2_kernel<<<8192, 256, 0, stream>>>(feats1, w1t, b1, ss1, feats2, partials);
  reduce_kernel<<<64, 256, 0, stream>>>(partials, stats2, 128);
  finalize_kernel<<<1, 64, 0, stream>>>(stats2, g1, be1, ss2, 64);
  gemm3_stats_kernel<<<8192, 256, 0, stream>>>(feats2, w2t, b2, ss2, partials, y3mx, y3mn);
  reduce_kernel<<<64, 256, 0, stream>>>(partials, stats3, 256);
  finalize_kernel<<<1, 128, 0, stream>>>(stats3, g2, be2, ss3, 128);
  bn3_out_kernel<<<512, 256, 0, stream>>>(y3mx, y3mn, ss3, out);
}

// Round 11
// 911.754 us; speedup vs baseline: 1.3541x; 1.0334x over previous
//
#include <hip/hip_runtime.h>
#include <hip/hip_bf16.h>
#include <cstdint>

// Problem constants
// B=16, N=4096, S=1024 (NPOINT), K=32 (NSAMPLE), CIN=64, MLP 67->64->64->128
// M = B*S*K = 524288 rows through the MLP.

typedef __attribute__((ext_vector_type(8))) short bf16x8;
typedef __attribute__((ext_vector_type(4))) float f32x4;

#define LDA 104   // bf16 LDS row stride: 208 B = 52 dwords -> 2-way (free) b128 bank pattern

__device__ __forceinline__ unsigned short f2bf(float f) {
  unsigned x = __float_as_uint(f);
  unsigned r = (x + 0x7FFFu + ((x >> 16) & 1u)) >> 16;  // RNE
  return (unsigned short)r;
}
__device__ __forceinline__ float bf2f(unsigned short u) {
  return __uint_as_float(((unsigned)u) << 16);
}

// DPP max-combine on a packed 64-bit key. DPP row ops are VALU-latency (~2-4cyc)
// vs ~120cyc for ds_permute-backed __shfl — this is the FPS critical path.
template <int CTRL>
__device__ __forceinline__ unsigned long long dppmax(unsigned long long k) {
  int lo = (int)(unsigned)k;
  int hi = (int)(unsigned)(k >> 32);
  int plo = __builtin_amdgcn_update_dpp(lo, lo, CTRL, 0xF, 0xF, false);
  int phi = __builtin_amdgcn_update_dpp(hi, hi, CTRL, 0xF, 0xF, false);
  unsigned long long o =
      ((unsigned long long)(unsigned)phi << 32) | (unsigned)plo;
  return (o > k) ? o : k;
}

// ---------------------------------------------------------------------------
// Fused FPS + prep, 256 threads/block. Blocks 0..15: FPS (one per batch).
// Blocks 16..1039: points transpose. Block 1040: weight tiles + stats zero.
//
// FPS STRUCTURAL FLOOR (r7-r9 measured): this exact kernel = 614us (r7).
// 8 waves = 666us (r8: barrier-phase-locked waves only add skew). Packed-f32
// + tree argmax = 879us (r9: f32x2 didn't map to clean v_pk, cndmask traffic
// doubled). The chain is 1024 serial iterations x ~1441cyc (dist issue ~416 +
// DPP + barrier + 2 dependent LDS rounds), confined to 1 CU/batch by the
// dist-state locality. Keep THIS version — do not re-tweak without disasm.
// amdgpu_waves_per_eu(1,1) is required: the default VGPR heuristic caps at
// 64 regs and spills the 64-float point arrays (r3-r5); launch_bounds cannot
// raise the max (r4).
// ---------------------------------------------------------------------------
__global__ __attribute__((amdgpu_flat_work_group_size(256, 256),
                          amdgpu_waves_per_eu(1, 1)))
void fps_prep_kernel(
    const float* __restrict__ xyz, const float* __restrict__ points,
    const float* __restrict__ W0, const float* __restrict__ W1,
    const float* __restrict__ W2, unsigned short* __restrict__ pT,
    unsigned short* __restrict__ w0t, unsigned short* __restrict__ w1t,
    unsigned short* __restrict__ w2t, float* __restrict__ stats_all,
    float* __restrict__ out, float4* __restrict__ centers4)
{
  __shared__ __align__(16) char smraw[61568];
  int tid = threadIdx.x;
  if (blockIdx.x >= 16) {
    int pb = blockIdx.x - 16;
    if (pb < 1024) {
      float (*tile)[65] = (float (*)[65])smraw;
      int b = pb >> 6;
      int n0 = (pb & 63) << 6;
      const float* pbp = points + ((size_t)b << 18);
      for (int i = tid; i < 4096; i += 256) {
        int cc = i >> 6, nn = i & 63;
        tile[cc][nn] = pbp[((size_t)cc << 12) + n0 + nn];
      }
      __syncthreads();
      for (int i = tid; i < 4096; i += 256) {
        int nn = i >> 6, cc = i & 63;
        pT[(((size_t)((b << 12) + n0 + nn)) << 6) + cc] = f2bf(tile[cc][nn]);
      }
    } else {
      // w0t: 64x104, w1t: 64x104, w2t: 128x104, stats: 512 floats
      for (int i = tid; i < 27136; i += 256) {
        if (i < 6656) {
          int nn = i / 104, kk = i % 104;
          float v = (kk < 64) ? W0[(3 + kk) * 64 + nn]
                              : ((kk < 67) ? W0[(kk - 64) * 64 + nn] : 0.f);
          w0t[i] = f2bf(v);
        } else if (i < 13312) {
          int j = i - 6656; int nn = j / 104, kk = j % 104;
          float v = (kk < 64) ? W1[kk * 64 + nn] : 0.f;
          w1t[j] = f2bf(v);
        } else if (i < 26624) {
          int j = i - 13312; int nn = j / 104, kk = j % 104;
          float v = (kk < 64) ? W2[kk * 128 + nn] : 0.f;
          w2t[j] = f2bf(v);
        } else {
          stats_all[i - 26624] = 0.f;
        }
      }
    }
    return;
  }
  // ---- FPS path ----
  float* xs  = (float*)smraw;                 // [4096]
  float* ys  = xs + 4096;                     // [4096]
  float* zs  = ys + 4096;                     // [4096]  (ends 49152 B)
  float* cxl = zs + 4096;                     // [1024]
  float* cyl = cxl + 1024;                    // [1024]
  float* czl = cyl + 1024;                    // [1024]  (ends 61440 B)
  unsigned long long (*keybuf)[4] =
      (unsigned long long (*)[4])(smraw + 61440);  // [2][4], 16B-aligned

  int b = blockIdx.x;
  const float* xb = xyz + (size_t)b * 12288;
  float px[16], py[16], pz[16], dist[16];
#pragma unroll
  for (int j = 0; j < 16; ++j) {
    int n = tid + (j << 8);
    px[j] = xb[n]; py[j] = xb[4096 + n]; pz[j] = xb[8192 + n];
    xs[n] = px[j]; ys[n] = py[j]; zs[n] = pz[j];
    dist[j] = 1e10f;
  }
  __syncthreads();
  float cx = xs[0], cy = ys[0], cz = zs[0];
  if (tid == 0) { cxl[0] = cx; cyl[0] = cy; czl[0] = cz; }
  int w = tid >> 6;
  int lane = tid & 63;
  for (int it = 1; it < 1024; ++it) {
    float bv = -1.f; int bi = 0;
#pragma unroll
    for (int j = 0; j < 16; ++j) {
      float dx = __fsub_rn(px[j], cx);
      float dy = __fsub_rn(py[j], cy);
      float dz = __fsub_rn(pz[j], cz);
      float d  = __fadd_rn(__fadd_rn(__fmul_rn(dx, dx), __fmul_rn(dy, dy)),
                           __fmul_rn(dz, dz));
      float nd = fminf(dist[j], d);
      dist[j] = nd;
      if (nd > bv) { bv = nd; bi = tid + (j << 8); }  // strict >, j asc => min n
    }
    // pack: high 32 = dist bits (nonneg float => monotone), low 32 = ~n
    unsigned long long k =
        ((unsigned long long)__float_as_uint(bv) << 32) | (unsigned)(~bi);
    k = dppmax<0xB1>(k);    // quad_perm [1,0,3,2]  : xor 1
    k = dppmax<0x4E>(k);    // quad_perm [2,3,0,1]  : xor 2
    k = dppmax<0x141>(k);   // row_half_mirror      : xor 4
    k = dppmax<0x140>(k);   // row_mirror           : xor 8
    k = dppmax<0x142>(k);   // row_bcast15          : rows 0->1, 2->3
    k = dppmax<0x143>(k);   // row_bcast31          : rows 01 -> 23
    int p = it & 1;
    if (lane == 63) keybuf[p][w] = k;   // lane63 holds the wave max
    __syncthreads();
    // combine 4 wave keys: 2x b128 reads + 3-compare tree (uniform)
    uint4 ka2 = *(const uint4*)&keybuf[p][0];
    uint4 kb2 = *(const uint4*)&keybuf[p][2];
    unsigned long long k0 = ((unsigned long long)ka2.y << 32) | ka2.x;
    unsigned long long k1 = ((unsigned long long)ka2.w << 32) | ka2.z;
    unsigned long long k2 = ((unsigned long long)kb2.y << 32) | kb2.x;
    unsigned long long k3 = ((unsigned long long)kb2.w << 32) | kb2.z;
    unsigned long long m01 = (k1 > k0) ? k1 : k0;
    unsigned long long m23 = (k3 > k2) ? k3 : k2;
    unsigned long long km  = (m23 > m01) ? m23 : m01;
    int gi = (int)(~(unsigned)km) & 4095;
    cx = xs[gi]; cy = ys[gi]; cz = zs[gi];
    if (tid == 0) { cxl[it] = cx; cyl[it] = cy; czl[it] = cz; }
    // no second barrier: next iter writes keybuf[(it+1)&1], disjoint slot;
    // a wave re-writes this slot only after passing the NEXT barrier, which
    // orders it after every wave's read above.
  }
  __syncthreads();
  for (int it = tid; it < 1024; it += 256) {
    float x = cxl[it], y = cyl[it], z = czl[it];
    out[b * 3072 + it]        = x;
    out[b * 3072 + 1024 + it] = y;
    out[b * 3072 + 2048 + it] = z;
    centers4[(b << 10) + it]  = make_float4(x, y, z, 0.f);
  }
}

// ---------------------------------------------------------------------------
// Ball query, wave-per-center. Each wave scans 64 points/chunk for ONE
// center; __ballot(hit) + prefix popcount assigns ranks; ranks <32 store
// (ascending n => identical to the reference's sort-then-take-32). Early
// exit per wave when cnt>=32. Round 7: dropped ball from 630us out of top-5.
// ---------------------------------------------------------------------------
__global__ __launch_bounds__(256) void ball_kernel(const float* __restrict__ xyz,
                                                   const float4* __restrict__ centers4,
                                                   int* __restrict__ ballidx)
{
  __shared__ float xs[4096], ys[4096], zs[4096];
  int tid = threadIdx.x;
  int b = blockIdx.x >> 4;          // 16 blocks per batch
  int g = blockIdx.x & 15;          // 64-center group within batch
  const float* xb = xyz + (size_t)b * 12288;
  for (int i = tid; i < 4096; i += 256) {
    xs[i] = xb[i]; ys[i] = xb[4096 + i]; zs[i] = xb[8192 + i];
  }
  __syncthreads();
  int w = tid >> 6, lane = tid & 63;
  unsigned long long lmask = (1ull << lane) - 1ull;
  for (int j = 0; j < 16; ++j) {
    int s = (g << 6) + (j << 2) + w;          // wave-interleaved centers
    float4 c = centers4[(b << 10) + s];
    int* ob = ballidx + (((size_t)((b << 10) + s)) << 5);
    int cnt = 0, first = 0;
    for (int m = 0; m < 64; ++m) {
      int n = (m << 6) + lane;
      float dx = __fsub_rn(xs[n], c.x);
      float dy = __fsub_rn(ys[n], c.y);
      float dz = __fsub_rn(zs[n], c.z);
      float d  = __fadd_rn(__fadd_rn(__fmul_rn(dx, dx), __fmul_rn(dy, dy)),
                           __fmul_rn(dz, dz));
      bool hit = !(d > 0.04f);      // 0.04f == f32(RADIUS**2), matches ref
      unsigned long long mask = __ballot(hit);
      if (cnt == 0 && mask != 0ull)
        first = (m << 6) + (__ffsll((long long)mask) - 1);
      int p = cnt + (int)__popcll(mask & lmask);
      if (hit && p < 32) ob[p] = n;
      cnt += (int)__popcll(mask);
      if (cnt >= 32) break;
    }
    // tail fill (cnt uniform across the wave; center itself always hits so cnt>=1)
    if (lane < 32 && lane >= cnt) ob[lane] = first;
  }
}

// ---------------------------------------------------------------------------
// GEMM1 (round 11: 256 rows/block, 4 sub-tiles — weight tile staged ONCE per
// block instead of once per 64 rows; 2048 blocks instead of 8192. Partials
// accumulate in registers across sub-tiles. The existing barrier pair per
// sub-tile provides all needed ordering for As/red reuse.)
// gather (pT rows + g_xyz) -> A[64 x 96(pad104)] bf16, W'T0, MFMA,
// write raw y1 bf16 [M,64] + per-block channel partials (sum, sumsq).
// ---------------------------------------------------------------------------
__global__ __launch_bounds__(256) void gemm1_kernel(
    const float* __restrict__ xyz, const unsigned short* __restrict__ pT,
    const unsigned short* __restrict__ w0t, const float* __restrict__ b0,
    const float4* __restrict__ centers4, const int* __restrict__ ballidx,
    unsigned short* __restrict__ feats1, float* __restrict__ partials)
{
  __shared__ unsigned short As[64 * LDA];
  __shared__ unsigned short Wt[64 * LDA];
  __shared__ float red[2][4][64];
  int tid = threadIdx.x;
  int blockbase = blockIdx.x << 8;   // 256 rows/block; stays within one batch
  int b = blockbase >> 15;
  {
    const uint4* wsrc = (const uint4*)w0t;
    uint4* wdst = (uint4*)Wt;
    for (int i = tid; i < 832; i += 256) wdst[i] = wsrc[i];
  }
  int lane = tid & 63, w = tid >> 6;
  int mrow = (w << 4) + (lane & 15);
  int quad = lane >> 4;
  float a0acc = 0.f, a1acc = 0.f;
  for (int t = 0; t < 4; ++t) {
    int rowbase = blockbase + (t << 6);
    {
      int rl = tid >> 2, part = tid & 3;
      int r = rowbase + rl;
      int n = ballidx[r];
      const uint4* psrc = (const uint4*)(pT + (((size_t)((b << 12) + n)) << 6));
      uint4* adst = (uint4*)(As + rl * LDA);
      adst[part * 2]     = psrc[part * 2];
      adst[part * 2 + 1] = psrc[part * 2 + 1];
      adst[8 + part] = make_uint4(0, 0, 0, 0);   // zero cols 64..95
      if (part == 0) {
        int ci = r >> 5;
        float4 c = centers4[ci];
        unsigned short* arow = As + rl * LDA;
        arow[64] = f2bf(__fsub_rn(xyz[(size_t)b * 12288 + n],        c.x));
        arow[65] = f2bf(__fsub_rn(xyz[(size_t)b * 12288 + 4096 + n], c.y));
        arow[66] = f2bf(__fsub_rn(xyz[(size_t)b * 12288 + 8192 + n], c.z));
      }
    }
    __syncthreads();
    f32x4 acc[4];
#pragma unroll
    for (int nt = 0; nt < 4; ++nt) acc[nt] = (f32x4){0.f, 0.f, 0.f, 0.f};
#pragma unroll
    for (int kt = 0; kt < 3; ++kt) {
      int ko = kt * 32 + (quad << 3);
      bf16x8 a = *(const bf16x8*)(As + mrow * LDA + ko);
#pragma unroll
      for (int nt = 0; nt < 4; ++nt) {
        bf16x8 bb = *(const bf16x8*)(Wt + ((nt << 4) + (lane & 15)) * LDA + ko);
        acc[nt] = __builtin_amdgcn_mfma_f32_16x16x32_bf16(a, bb, acc[nt], 0, 0, 0);
      }
    }
#pragma unroll
    for (int nt = 0; nt < 4; ++nt) {
      int cch = (nt << 4) + (lane & 15);
      float bias = b0[cch];
      float ssum = 0.f, sq = 0.f;
#pragma unroll
      for (int r2 = 0; r2 < 4; ++r2) {
        float y = acc[nt][r2] + bias;
        int ml = (w << 4) + (quad << 2) + r2;
        feats1[(((size_t)(rowbase + ml)) << 6) + cch] = f2bf(y);
        ssum += y; sq += y * y;
      }
      ssum += __shfl_xor(ssum, 16); ssum += __shfl_xor(ssum, 32);
      sq   += __shfl_xor(sq, 16);   sq   += __shfl_xor(sq, 32);
      if (quad == 0) { red[0][w][cch] = ssum; red[1][w][cch] = sq; }
    }
    __syncthreads();
    if (tid < 64) {
      a0acc += red[0][0][tid] + red[0][1][tid] + red[0][2][tid] + red[0][3][tid];
      a1acc += red[1][0][tid] + red[1][1][tid] + red[1][2][tid] + red[1][3][tid];
    }
    // next sub-tile's As/red overwrites happen after its staging barrier,
    // which every thread reaches only after the reads above (program order
    // + barrier) — no extra sync needed.
  }
  if (tid < 64) {
    partials[(size_t)blockIdx.x * 256 + tid]      = a0acc;
    partials[(size_t)blockIdx.x * 256 + 64 + tid] = a1acc;
  }
}

// ---------------------------------------------------------------------------
// GEMM2 (256 rows/block, 4 sub-tiles): A = relu(scale*y1+shift) from feats1;
// K=64; out raw y2 + partials.
// ---------------------------------------------------------------------------
__global__ __launch_bounds__(256) void gemm2_kernel(
    const unsigned short* __restrict__ featsIn, const unsigned short* __restrict__ wt,
    const float* __restrict__ bias_g, const float* __restrict__ ss_in,
    unsigned short* __restrict__ featsOut, float* __restrict__ partials)
{
  __shared__ unsigned short As[64 * LDA];
  __shared__ unsigned short Wt[64 * LDA];
  __shared__ float red[2][4][64];
  __shared__ float ssl[128];
  int tid = threadIdx.x;
  int blockbase = blockIdx.x << 8;
  if (tid < 128) ssl[tid] = ss_in[tid];
  {
    const uint4* wsrc = (const uint4*)wt;
    uint4* wdst = (uint4*)Wt;
    for (int i = tid; i < 832; i += 256) wdst[i] = wsrc[i];
  }
  int lane = tid & 63, w = tid >> 6;
  int mrow = (w << 4) + (lane & 15);
  int quad = lane >> 4;
  float a0acc = 0.f, a1acc = 0.f;
  __syncthreads();           // ssl/Wt visible before first use
  for (int t = 0; t < 4; ++t) {
    int rowbase = blockbase + (t << 6);
    {
      int rl = tid >> 2, part = tid & 3;
      size_t r = (size_t)rowbase + rl;
      union { uint4 v[2]; unsigned short u[16]; } tt;
      const uint4* src = (const uint4*)(featsIn + (r << 6));
      tt.v[0] = src[part * 2]; tt.v[1] = src[part * 2 + 1];
      union { uint4 v[2]; unsigned short u[16]; } o;
#pragma unroll
      for (int e = 0; e < 16; ++e) {
        int cch = (part << 4) + e;
        float f = bf2f(tt.u[e]);
        float y = fmaxf(f * ssl[cch] + ssl[64 + cch], 0.f);
        o.u[e] = f2bf(y);
      }
      uint4* adst = (uint4*)(As + rl * LDA + (part << 4));
      adst[0] = o.v[0]; adst[1] = o.v[1];
    }
    __syncthreads();
    f32x4 acc[4];
#pragma unroll
    for (int nt = 0; nt < 4; ++nt) acc[nt] = (f32x4){0.f, 0.f, 0.f, 0.f};
#pragma unroll
    for (int kt = 0; kt < 2; ++kt) {
      int ko = kt * 32 + (quad << 3);
      bf16x8 a = *(const bf16x8*)(As + mrow * LDA + ko);
#pragma unroll
      for (int nt = 0; nt < 4; ++nt) {
        bf16x8 bb = *(const bf16x8*)(Wt + ((nt << 4) + (lane & 15)) * LDA + ko);
        acc[nt] = __builtin_amdgcn_mfma_f32_16x16x32_bf16(a, bb, acc[nt], 0, 0, 0);
      }
    }
#pragma unroll
    for (int nt = 0; nt < 4; ++nt) {
      int cch = (nt << 4) + (lane & 15);
      float bias = bias_g[cch];
      float ssum = 0.f, sq = 0.f;
#pragma unroll
      for (int r2 = 0; r2 < 4; ++r2) {
        float y = acc[nt][r2] + bias;
        int ml = (w << 4) + (quad << 2) + r2;
        featsOut[(((size_t)(rowbase + ml)) << 6) + cch] = f2bf(y);
        ssum += y; sq += y * y;
      }
      ssum += __shfl_xor(ssum, 16); ssum += __shfl_xor(ssum, 32);
      sq   += __shfl_xor(sq, 16);   sq   += __shfl_xor(sq, 32);
      if (quad == 0) { red[0][w][cch] = ssum; red[1][w][cch] = sq; }
    }
    __syncthreads();
    if (tid < 64) {
      a0acc += red[0][0][tid] + red[0][1][tid] + red[0][2][tid] + red[0][3][tid];
      a1acc += red[1][0][tid] + red[1][1][tid] + red[1][2][tid] + red[1][3][tid];
    }
  }
  if (tid < 64) {
    partials[(size_t)blockIdx.x * 256 + tid]      = a0acc;
    partials[(size_t)blockIdx.x * 256 + 64 + tid] = a1acc;
  }
}

// ---------------------------------------------------------------------------
// GEMM3 stats + K-extremes (256 rows/block, 4 sub-tiles): y3 =
// relu2(feats2)@W2 + b2. Channel partials (sum,sumsq) accumulate across
// sub-tiles; per-(center,channel) max/min of raw y3 written per sub-tile
// (2 centers each). max_k relu(sc*y+sh) == relu(sc*(sc>=0?max:min)+sh)
// bit-exactly (IEEE-RN mul/add weak monotonicity) — replaces final_kernel.
// ---------------------------------------------------------------------------
__global__ __launch_bounds__(256) void gemm3_stats_kernel(
    const unsigned short* __restrict__ feats2, const unsigned short* __restrict__ w2t,
    const float* __restrict__ b2, const float* __restrict__ ss2,
    float* __restrict__ partials, float* __restrict__ y3mx,
    float* __restrict__ y3mn)
{
  __shared__ unsigned short As[64 * LDA];
  __shared__ unsigned short Wt[128 * LDA];
  __shared__ float red[2][4][128];
  __shared__ float mxw[4][128];
  __shared__ float mnw[4][128];
  __shared__ float ssl[128];
  int tid = threadIdx.x;
  int blockbase = blockIdx.x << 8;
  if (tid < 128) ssl[tid] = ss2[tid];
  {
    const uint4* wsrc = (const uint4*)w2t;
    uint4* wdst = (uint4*)Wt;
    for (int i = tid; i < 1664; i += 256) wdst[i] = wsrc[i];
  }
  int lane = tid & 63, w = tid >> 6;
  int mrow = (w << 4) + (lane & 15);
  int quad = lane >> 4;
  float a0acc = 0.f, a1acc = 0.f;
  __syncthreads();
  for (int t = 0; t < 4; ++t) {
    int rowbase = blockbase + (t << 6);
    {
      int rl = tid >> 2, part = tid & 3;
      size_t r = (size_t)rowbase + rl;
      union { uint4 v[2]; unsigned short u[16]; } tt;
      const uint4* src = (const uint4*)(feats2 + (r << 6));
      tt.v[0] = src[part * 2]; tt.v[1] = src[part * 2 + 1];
      union { uint4 v[2]; unsigned short u[16]; } o;
#pragma unroll
      for (int e = 0; e < 16; ++e) {
        int cch = (part << 4) + e;
        float f = bf2f(tt.u[e]);
        float y = fmaxf(f * ssl[cch] + ssl[64 + cch], 0.f);
        o.u[e] = f2bf(y);
      }
      uint4* adst = (uint4*)(As + rl * LDA + (part << 4));
      adst[0] = o.v[0]; adst[1] = o.v[1];
    }
    __syncthreads();
    f32x4 acc[8];
#pragma unroll
    for (int nt = 0; nt < 8; ++nt) acc[nt] = (f32x4){0.f, 0.f, 0.f, 0.f};
#pragma unroll
    for (int kt = 0; kt < 2; ++kt) {
      int ko = kt * 32 + (quad << 3);
      bf16x8 a = *(const bf16x8*)(As + mrow * LDA + ko);
#pragma unroll
      for (int nt = 0; nt < 8; ++nt) {
        bf16x8 bb = *(const bf16x8*)(Wt + ((nt << 4) + (lane & 15)) * LDA + ko);
        acc[nt] = __builtin_amdgcn_mfma_f32_16x16x32_bf16(a, bb, acc[nt], 0, 0, 0);
      }
    }
    // wave w's 16 rows belong to one center (center = w>>1 within sub-tile)
#pragma unroll
    for (int nt = 0; nt < 8; ++nt) {
      int cch = (nt << 4) + (lane & 15);
      float bias = b2[cch];
      float ssum = 0.f, sq = 0.f;
      float mx = -3.4e38f, mn = 3.4e38f;
#pragma unroll
      for (int r2 = 0; r2 < 4; ++r2) {
        float y = acc[nt][r2] + bias;
        ssum += y; sq += y * y;
        mx = fmaxf(mx, y); mn = fminf(mn, y);
      }
      ssum += __shfl_xor(ssum, 16); ssum += __shfl_xor(ssum, 32);
      sq   += __shfl_xor(sq, 16);   sq   += __shfl_xor(sq, 32);
      mx = fmaxf(mx, __shfl_xor(mx, 16)); mx = fmaxf(mx, __shfl_xor(mx, 32));
      mn = fminf(mn, __shfl_xor(mn, 16)); mn = fminf(mn, __shfl_xor(mn, 32));
      if (quad == 0) {
        red[0][w][cch] = ssum; red[1][w][cch] = sq;
        mxw[w][cch] = mx; mnw[w][cch] = mn;
      }
    }
    __syncthreads();
    if (tid < 128) {
      a0acc += red[0][0][tid] + red[0][1][tid] + red[0][2][tid] + red[0][3][tid];
      a1acc += red[1][0][tid] + red[1][1][tid] + red[1][2][tid] + red[1][3][tid];
    }
    {
      int c2 = tid >> 7, cch = tid & 127;
      int cg = (rowbase >> 5) + c2;          // global center index b*1024+s
      y3mx[((size_t)cg << 7) + cch] = fmaxf(mxw[2 * c2][cch], mxw[2 * c2 + 1][cch]);
      y3mn[((size_t)cg << 7) + cch] = fminf(mnw[2 * c2][cch], mnw[2 * c2 + 1][cch]);
    }
  }
  if (tid < 128) {
    partials[(size_t)blockIdx.x * 256 + tid]       = a0acc;
    partials[(size_t)blockIdx.x * 256 + 128 + tid] = a1acc;
  }
}

// ---------------------------------------------------------------------------
// stats reduce (partials now 2048 rows: 64 blocks x 32 rows) + finalize
// ---------------------------------------------------------------------------
__global__ __launch_bounds__(256) void reduce_kernel(const float* __restrict__ partials,
                                                     float* __restrict__ stats, int twoC)
{
  int tid = threadIdx.x;
  if (tid < twoC) {
    int row0 = blockIdx.x << 5;
    float s = 0.f;
    for (int r = 0; r < 32; ++r) s += partials[((size_t)(row0 + r)) * 256 + tid];
    atomicAdd(&stats[tid], s);
  }
}

__global__ void finalize_kernel(const float* __restrict__ stats, const float* __restrict__ g,
                                const float* __restrict__ be, float* __restrict__ ss, int C)
{
  int c = threadIdx.x;
  if (c < C) {
    const float invM = 1.f / 524288.f;
    float mean = stats[c] * invM;
    float ex2  = stats[C + c] * invM;
    float var  = ex2 - mean * mean;
    float sc   = g[c] / sqrtf(var + 1e-5f);
    ss[c]     = sc;
    ss[C + c] = be[c] - mean * sc;
  }
}

// ---------------------------------------------------------------------------
// BN3 + K-max epilogue + transpose: read y3mx/y3mn [B*S,128], pick extreme by
// sign(sc), apply relu(sc*y+sh), write d_out [B,128,S] (offset 49152).
// ---------------------------------------------------------------------------
__global__ __launch_bounds__(256) void bn3_out_kernel(
    const float* __restrict__ y3mx, const float* __restrict__ y3mn,
    const float* __restrict__ ss3, float* __restrict__ out)
{
  __shared__ float t2[64][65];
  __shared__ float sl[128];
  int tid = threadIdx.x;
  int b = blockIdx.x >> 5;
  int rest = blockIdx.x & 31;
  int s0 = (rest & 15) << 6;
  int c0 = (rest >> 4) << 6;
  if (tid < 64) sl[tid] = ss3[c0 + tid];
  else if (tid < 128) sl[tid] = ss3[128 + c0 + (tid - 64)];
  __syncthreads();
  for (int i = tid; i < 4096; i += 256) {
    int row = i >> 6, col = i & 63;         // row = s within tile, col = ch
    size_t cg = (size_t)((b << 10) + s0 + row);
    float mx = y3mx[(cg << 7) + c0 + col];
    float mn = y3mn[(cg << 7) + c0 + col];
    float sc = sl[col], sh = sl[64 + col];
    float ye = (sc >= 0.f) ? mx : mn;
    t2[row][col] = fmaxf(ye * sc + sh, 0.f);
  }
  __syncthreads();
  for (int i = tid; i < 4096; i += 256) {
    int crow = i >> 6, scol = i & 63;
    out[49152 + ((size_t)b << 17) + (size_t)(c0 + crow) * 1024 + s0 + scol] = t2[scol][crow];
  }
}

// ---------------------------------------------------------------------------
extern "C" void kernel_launch(void* const* d_in, const int* in_sizes, int n_in,
                              void* d_out, int out_size, void* d_ws, size_t ws_size,
                              hipStream_t stream)
{
  (void)in_sizes; (void)n_in; (void)out_size; (void)ws_size;
  const float* xyz    = (const float*)d_in[0];
  const float* points = (const float*)d_in[1];
  const float* W0  = (const float*)d_in[2];
  const float* b0  = (const float*)d_in[3];
  const float* g0  = (const float*)d_in[4];
  const float* be0 = (const float*)d_in[5];
  const float* W1  = (const float*)d_in[6];
  const float* b1  = (const float*)d_in[7];
  const float* g1  = (const float*)d_in[8];
  const float* be1 = (const float*)d_in[9];
  const float* W2  = (const float*)d_in[10];
  const float* b2  = (const float*)d_in[11];
  const float* g2  = (const float*)d_in[12];
  const float* be2 = (const float*)d_in[13];
  float* out = (float*)d_out;

  char* base = (char*)d_ws;
  size_t off = 0;
  auto alloc = [&](size_t bytes) -> void* {
    void* p = base + off;
    off += (bytes + 255) & ~(size_t)255;
    return p;
  };
  unsigned short* pT     = (unsigned short*)alloc((size_t)16 * 4096 * 64 * 2);
  unsigned short* w0t    = (unsigned short*)alloc(64 * LDA * 2);
  unsigned short* w1t    = (unsigned short*)alloc(64 * LDA * 2);
  unsigned short* w2t    = (unsigned short*)alloc(128 * LDA * 2);
  float* stats_all       = (float*)alloc(512 * 4);
  float* ss_all          = (float*)alloc(512 * 4);
  float4* centers4       = (float4*)alloc((size_t)16 * 1024 * 16);
  int* ballidx           = (int*)alloc((size_t)16 * 1024 * 32 * 4);
  unsigned short* feats1 = (unsigned short*)alloc((size_t)524288 * 64 * 2);
  unsigned short* feats2 = (unsigned short*)alloc((size_t)524288 * 64 * 2);
  float* partials        = (float*)alloc((size_t)2048 * 256 * 4);

  // y3 extremes overlay the dead feats1 buffer (feats1 is fully consumed by
  // gemm2 before gemm3_stats runs; 2 x 8.4MB fits in feats1's 67MB).
  float* y3mx = (float*)feats1;
  float* y3mn = y3mx + (size_t)16384 * 128;

  float* stats1 = stats_all;       float* stats2 = stats_all + 128; float* stats3 = stats_all + 256;
  float* ss1 = ss_all;             float* ss2 = ss_all + 128;       float* ss3 = ss_all + 256;

  fps_prep_kernel<<<1041, 256, 0, stream>>>(xyz, points, W0, W1, W2, pT, w0t, w1t,
                                            w2t, stats_all, out, centers4);
  ball_kernel<<<256, 256, 0, stream>>>(xyz, centers4, ballidx);
  gemm1_kernel<<<2048, 256, 0, stream>>>(xyz, pT, w0t, b0, centers4, ballidx, feats1, partials);
  reduce_kernel<<<64, 256, 0, stream>>>(partials, stats1, 128);
  finalize_kernel<<<1, 64, 0, stream>>>(stats1, g0, be0, ss1, 64);
  gemm2_kernel<<<2048, 256, 0, stream>>>(feats1, w1t, b1, ss1, feats2, partials);
  reduce_kernel<<<64, 256, 0, stream>>>(partials, stats2, 128);
  finalize_kernel<<<1, 64, 0, stream>>>(stats2, g1, be1, ss2, 64);
  gemm3_stats_kernel<<<2048, 256, 0, stream>>>(feats2, w2t, b2, ss2, partials, y3mx, y3mn);
  reduce_kernel<<<64, 256, 0, stream>>>(partials, stats3, 256);
  finalize_kernel<<<1, 128, 0, stream>>>(stats3, g2, be2, ss3, 128);
  bn3_out_kernel<<<512, 256, 0, stream>>>(y3mx, y3mn, ss3, out);
}